// Round 2
// baseline (133.647 us; speedup 1.0000x reference)
//
#include <hip/hip_runtime.h>
#include <hip/hip_bf16.h>
#include <math.h>

// Problem constants
constexpr int B = 64;
constexpr int S = 2048;
constexpr int D = 512;
constexpr int NCHUNK = 8;           // s-chunks per b
constexpr int CHUNK = S / NCHUNK;   // 256 rows per block
constexpr int TS = 16;              // tile rows staged in LDS
constexpr int NTILE = CHUNK / TS;   // 16 tiles per block
constexpr int NW = 4;               // waves per block
constexpr int RPW = TS / NW;        // 4 rows per wave per tile
constexpr int NPART = NCHUNK * NW;  // 32 partials per b

// ---------------------------------------------------------------------------
// Kernel 1: v[c][b][d] = bias[d] + sum_e K[d][e] * c_c[b][e]
// ---------------------------------------------------------------------------
__global__ __launch_bounds__(256) void compute_v_kernel(
    const float* __restrict__ K, const float* __restrict__ bias,
    const float* __restrict__ c1, const float* __restrict__ c2,
    const float* __restrict__ c3, const float* __restrict__ c4,
    float* __restrict__ v)
{
    const int b = blockIdx.y;
    const int dchunk = blockIdx.x;   // 64 rows each
    __shared__ float c_lds[4][D];

    const float* cptr0 = c1 + (size_t)b * D;
    const float* cptr1 = c2 + (size_t)b * D;
    const float* cptr2 = c3 + (size_t)b * D;
    const float* cptr3 = c4 + (size_t)b * D;
    for (int i = threadIdx.x; i < D; i += 256) {
        c_lds[0][i] = cptr0[i];
        c_lds[1][i] = cptr1[i];
        c_lds[2][i] = cptr2[i];
        c_lds[3][i] = cptr3[i];
    }
    __syncthreads();

    const int wave = threadIdx.x >> 6;
    const int lane = threadIdx.x & 63;

    #pragma unroll
    for (int r = 0; r < 16; ++r) {
        const int d = dchunk * 64 + wave * 16 + r;
        const float* krow = K + (size_t)d * D;
        float a0 = 0.f, a1 = 0.f, a2 = 0.f, a3 = 0.f;
        #pragma unroll
        for (int k = 0; k < D / 64; ++k) {
            const float kv = krow[k * 64 + lane];
            a0 = fmaf(kv, c_lds[0][k * 64 + lane], a0);
            a1 = fmaf(kv, c_lds[1][k * 64 + lane], a1);
            a2 = fmaf(kv, c_lds[2][k * 64 + lane], a2);
            a3 = fmaf(kv, c_lds[3][k * 64 + lane], a3);
        }
        #pragma unroll
        for (int off = 32; off; off >>= 1) {
            a0 += __shfl_xor(a0, off);
            a1 += __shfl_xor(a1, off);
            a2 += __shfl_xor(a2, off);
            a3 += __shfl_xor(a3, off);
        }
        if (lane == 0) {
            const float bv = bias[d];
            v[((size_t)0 * B + b) * D + d] = a0 + bv;
            v[((size_t)1 * B + b) * D + d] = a1 + bv;
            v[((size_t)2 * B + b) * D + d] = a2 + bv;
            v[((size_t)3 * B + b) * D + d] = a3 + bv;
        }
    }
}

// ---------------------------------------------------------------------------
// Kernel 2: flash pass over sent. Per-wave independent online softmax.
// grid (NCHUNK, B), 256 threads (4 waves). Lane owns d in {4l..4l+3} and
// {256+4l..256+4l+3}; lane's softmax scalar state is for c = lane&3.
// Double-buffered LDS tile, reg-staged loads overlapped with compute.
// ---------------------------------------------------------------------------
__global__ __launch_bounds__(256, 2) void flash_kernel(
    const float* __restrict__ sent, const float* __restrict__ v,
    float* __restrict__ partML, float* __restrict__ partP)
{
    const int b = blockIdx.y;
    const int ch = blockIdx.x;
    const int t = threadIdx.x;
    const int wave = t >> 6;
    const int lane = t & 63;

    __shared__ float tile[2][TS * D];   // 2 x 32 KB

    // v fragments in registers: vlo[c][j] = v[c][b][4*lane+j], vhi -> +256
    float vlo[4][4], vhi[4][4];
    #pragma unroll
    for (int c = 0; c < 4; ++c) {
        const float4 lo = *(const float4*)&v[((size_t)c * B + b) * D + lane * 4];
        const float4 hi = *(const float4*)&v[((size_t)c * B + b) * D + 256 + lane * 4];
        vlo[c][0] = lo.x; vlo[c][1] = lo.y; vlo[c][2] = lo.z; vlo[c][3] = lo.w;
        vhi[c][0] = hi.x; vhi[c][1] = hi.y; vhi[c][2] = hi.z; vhi[c][3] = hi.w;
    }

    const size_t sbase = ((size_t)b * S + (size_t)ch * CHUNK) * D;

    // prologue: stage tile 0
    float4 stg[8];
    {
        const float4* src = (const float4*)(sent + sbase);
        #pragma unroll
        for (int i = 0; i < 8; ++i) stg[i] = src[i * 256 + t];
        float4* dst = (float4*)tile[0];
        #pragma unroll
        for (int i = 0; i < 8; ++i) dst[i * 256 + t] = stg[i];
    }
    __syncthreads();

    float m = -INFINITY, lsum = 0.f;          // state for c = lane&3
    float plo[4][4] = {{0}}, phi[4][4] = {{0}};  // P[c][j] for lane's d-slice

    for (int tl = 0; tl < NTILE; ++tl) {
        const int buf = tl & 1;

        // issue next tile's global loads early (hide HBM latency under compute)
        if (tl + 1 < NTILE) {
            const float4* src = (const float4*)(sent + sbase + (size_t)(tl + 1) * TS * D);
            #pragma unroll
            for (int i = 0; i < 8; ++i) stg[i] = src[i * 256 + t];
        }

        // ---- scores for this wave's 4 rows
        float x[RPW][8];
        float s[RPW];
        #pragma unroll
        for (int rr = 0; rr < RPW; ++rr) {
            const int r = wave * RPW + rr;
            const float4 xlo = *(const float4*)&tile[buf][r * D + lane * 4];
            const float4 xhi = *(const float4*)&tile[buf][r * D + 256 + lane * 4];
            x[rr][0] = xlo.x; x[rr][1] = xlo.y; x[rr][2] = xlo.z; x[rr][3] = xlo.w;
            x[rr][4] = xhi.x; x[rr][5] = xhi.y; x[rr][6] = xhi.z; x[rr][7] = xhi.w;
            float a0 = 0.f, a1 = 0.f, a2 = 0.f, a3 = 0.f;
            #pragma unroll
            for (int j = 0; j < 4; ++j) {
                a0 = fmaf(x[rr][j], vlo[0][j], a0); a0 = fmaf(x[rr][4 + j], vhi[0][j], a0);
                a1 = fmaf(x[rr][j], vlo[1][j], a1); a1 = fmaf(x[rr][4 + j], vhi[1][j], a1);
                a2 = fmaf(x[rr][j], vlo[2][j], a2); a2 = fmaf(x[rr][4 + j], vhi[2][j], a2);
                a3 = fmaf(x[rr][j], vlo[3][j], a3); a3 = fmaf(x[rr][4 + j], vhi[3][j], a3);
            }
            // folded 4-value butterfly: 6 shfl total, result for c=lane&3
            float u  = (lane & 1) ? a1 : a0;
            float uo = (lane & 1) ? a0 : a1;
            u += __shfl_xor(uo, 1);
            float w_ = (lane & 1) ? a3 : a2;
            float wo = (lane & 1) ? a2 : a3;
            w_ += __shfl_xor(wo, 1);
            float p  = (lane & 2) ? w_ : u;
            float q  = (lane & 2) ? u : w_;
            p += __shfl_xor(q, 2);
            p += __shfl_xor(p, 4);
            p += __shfl_xor(p, 8);
            p += __shfl_xor(p, 16);
            p += __shfl_xor(p, 32);
            s[rr] = p;
        }

        // ---- online softmax update for own c
        const float tm = fmaxf(fmaxf(s[0], s[1]), fmaxf(s[2], s[3]));
        const float mn = fmaxf(m, tm);
        const float cr = __expf(m - mn);    // first tile: exp(-inf)=0
        m = mn;
        lsum *= cr;
        float w4[RPW];
        #pragma unroll
        for (int rr = 0; rr < RPW; ++rr) { w4[rr] = __expf(s[rr] - mn); lsum += w4[rr]; }

        // ---- rescale P (broadcast cr_c via readlane: lane c holds c's state)
        #pragma unroll
        for (int c = 0; c < 4; ++c) {
            const float crc = __int_as_float(__builtin_amdgcn_readlane(__float_as_int(cr), c));
            #pragma unroll
            for (int j = 0; j < 4; ++j) { plo[c][j] *= crc; phi[c][j] *= crc; }
        }
        // ---- accumulate P from the x regs already loaded
        #pragma unroll
        for (int rr = 0; rr < RPW; ++rr) {
            #pragma unroll
            for (int c = 0; c < 4; ++c) {
                const float wc = __int_as_float(__builtin_amdgcn_readlane(__float_as_int(w4[rr]), c));
                plo[c][0] = fmaf(wc, x[rr][0], plo[c][0]);
                plo[c][1] = fmaf(wc, x[rr][1], plo[c][1]);
                plo[c][2] = fmaf(wc, x[rr][2], plo[c][2]);
                plo[c][3] = fmaf(wc, x[rr][3], plo[c][3]);
                phi[c][0] = fmaf(wc, x[rr][4], phi[c][0]);
                phi[c][1] = fmaf(wc, x[rr][5], phi[c][1]);
                phi[c][2] = fmaf(wc, x[rr][6], phi[c][2]);
                phi[c][3] = fmaf(wc, x[rr][7], phi[c][3]);
            }
        }

        __syncthreads();   // all waves done reading tile[buf^1]'s predecessor & tile[buf]
        if (tl + 1 < NTILE) {
            float4* dst = (float4*)tile[buf ^ 1];
            #pragma unroll
            for (int i = 0; i < 8; ++i) dst[i * 256 + t] = stg[i];
        }
        __syncthreads();   // next tile ready
    }

    // ---- write per-wave partial
    const int pi = (b * NCHUNK + ch) * NW + wave;
    #pragma unroll
    for (int c = 0; c < 4; ++c) {
        const float4 lo4 = make_float4(plo[c][0], plo[c][1], plo[c][2], plo[c][3]);
        const float4 hi4 = make_float4(phi[c][0], phi[c][1], phi[c][2], phi[c][3]);
        *(float4*)&partP[((size_t)pi * 4 + c) * D + lane * 4] = lo4;
        *(float4*)&partP[((size_t)pi * 4 + c) * D + 256 + lane * 4] = hi4;
    }
    if (lane < 4) {   // lane == c
        partML[(pi * 4 + lane) * 2 + 0] = m;
        partML[(pi * 4 + lane) * 2 + 1] = lsum;
    }
}

// ---------------------------------------------------------------------------
// Kernel 3: merge the 32 per-wave partials per (c,b), normalize, write out.
// ---------------------------------------------------------------------------
__global__ __launch_bounds__(128) void combine_kernel(
    const float* __restrict__ partML, const float* __restrict__ partP,
    float* __restrict__ out)
{
    const int c = blockIdx.x & 3;
    const int b = blockIdx.x >> 2;
    const int t = threadIdx.x;
    const int base_pi = b * NPART;

    float mg = -INFINITY;
    for (int i = 0; i < NPART; ++i)
        mg = fmaxf(mg, partML[((base_pi + i) * 4 + c) * 2 + 0]);

    float lg = 0.f;
    float4 acc = make_float4(0.f, 0.f, 0.f, 0.f);
    for (int i = 0; i < NPART; ++i) {
        const float mi = partML[((base_pi + i) * 4 + c) * 2 + 0];
        const float li = partML[((base_pi + i) * 4 + c) * 2 + 1];
        const float sc = __expf(mi - mg);
        lg += sc * li;
        const float4 p = *(const float4*)&partP[((size_t)(base_pi + i) * 4 + c) * D + t * 4];
        acc.x = fmaf(sc, p.x, acc.x);
        acc.y = fmaf(sc, p.y, acc.y);
        acc.z = fmaf(sc, p.z, acc.z);
        acc.w = fmaf(sc, p.w, acc.w);
    }
    const float inv = 1.f / lg;
    acc.x *= inv; acc.y *= inv; acc.z *= inv; acc.w *= inv;
    *(float4*)&out[((size_t)c * B + b) * D + t * 4] = acc;
}

// ---------------------------------------------------------------------------
extern "C" void kernel_launch(void* const* d_in, const int* in_sizes, int n_in,
                              void* d_out, int out_size, void* d_ws, size_t ws_size,
                              hipStream_t stream)
{
    const float* sent = (const float*)d_in[0];
    const float* c1   = (const float*)d_in[1];
    const float* c2   = (const float*)d_in[2];
    const float* c3   = (const float*)d_in[3];
    const float* c4   = (const float*)d_in[4];
    const float* K    = (const float*)d_in[5];
    const float* bias = (const float*)d_in[6];
    float* out = (float*)d_out;

    // workspace layout (all 16B-aligned)
    float* v      = (float*)d_ws;                                   // 512 KB
    float* partML = (float*)((char*)d_ws + 4 * B * D * 4);          // 64 KB
    float* partP  = (float*)((char*)d_ws + 4 * B * D * 4
                             + B * NPART * 4 * 2 * 4);              // 16 MB

    compute_v_kernel<<<dim3(8, B), 256, 0, stream>>>(K, bias, c1, c2, c3, c4, v);
    flash_kernel<<<dim3(NCHUNK, B), 256, 0, stream>>>(sent, v, partML, partP);
    combine_kernel<<<4 * B, 128, 0, stream>>>(partML, partP, out);
}

// Round 3
// 74.796 us; speedup vs baseline: 1.7868x; 1.7868x over previous
//
#include <hip/hip_runtime.h>
#include <hip/hip_bf16.h>
#include <math.h>

// Problem constants
constexpr int B = 64;
constexpr int S = 2048;
constexpr int D = 512;
constexpr int NCHUNK = 8;           // s-chunks per b
constexpr int CHUNK = S / NCHUNK;   // 256 rows per block
constexpr int NW = 4;               // waves per block
constexpr int ROWS_PER_WAVE = CHUNK / NW;   // 64
constexpr int NGRP = ROWS_PER_WAVE / 4;     // 16 groups of 4 rows
constexpr int NPART = NCHUNK * NW;  // 32 partials per b

// ---------------------------------------------------------------------------
// Kernel 1: v[c][b][d] = bias[d] + sum_e K[d][e] * c_c[b][e]
// ---------------------------------------------------------------------------
__global__ __launch_bounds__(256) void compute_v_kernel(
    const float* __restrict__ K, const float* __restrict__ bias,
    const float* __restrict__ c1, const float* __restrict__ c2,
    const float* __restrict__ c3, const float* __restrict__ c4,
    float* __restrict__ v)
{
    const int b = blockIdx.y;
    const int dchunk = blockIdx.x;   // 64 rows each
    __shared__ float c_lds[4][D];

    const float* cptr0 = c1 + (size_t)b * D;
    const float* cptr1 = c2 + (size_t)b * D;
    const float* cptr2 = c3 + (size_t)b * D;
    const float* cptr3 = c4 + (size_t)b * D;
    for (int i = threadIdx.x; i < D; i += 256) {
        c_lds[0][i] = cptr0[i];
        c_lds[1][i] = cptr1[i];
        c_lds[2][i] = cptr2[i];
        c_lds[3][i] = cptr3[i];
    }
    __syncthreads();

    const int wave = threadIdx.x >> 6;
    const int lane = threadIdx.x & 63;

    #pragma unroll
    for (int r = 0; r < 16; ++r) {
        const int d = dchunk * 64 + wave * 16 + r;
        const float* krow = K + (size_t)d * D;
        float a0 = 0.f, a1 = 0.f, a2 = 0.f, a3 = 0.f;
        #pragma unroll
        for (int k = 0; k < D / 64; ++k) {
            const float kv = krow[k * 64 + lane];
            a0 = fmaf(kv, c_lds[0][k * 64 + lane], a0);
            a1 = fmaf(kv, c_lds[1][k * 64 + lane], a1);
            a2 = fmaf(kv, c_lds[2][k * 64 + lane], a2);
            a3 = fmaf(kv, c_lds[3][k * 64 + lane], a3);
        }
        #pragma unroll
        for (int off = 32; off; off >>= 1) {
            a0 += __shfl_xor(a0, off);
            a1 += __shfl_xor(a1, off);
            a2 += __shfl_xor(a2, off);
            a3 += __shfl_xor(a3, off);
        }
        if (lane == 0) {
            const float bv = bias[d];
            v[((size_t)0 * B + b) * D + d] = a0 + bv;
            v[((size_t)1 * B + b) * D + d] = a1 + bv;
            v[((size_t)2 * B + b) * D + d] = a2 + bv;
            v[((size_t)3 * B + b) * D + d] = a3 + bv;
        }
    }
}

// ---------------------------------------------------------------------------
// Kernel 2: flash pass over sent. NO LDS, NO barriers — each wave streams its
// own 64 rows directly from global (coalesced 1KB segments per row), software
// pipelined in register groups of 4 rows (xA/xB). Per-wave online softmax;
// lane's scalar softmax state is for c = lane&3; lane owns d-slices
// {4l..4l+3} and {256+4l..256+4l+3}.
// ---------------------------------------------------------------------------
__global__ __launch_bounds__(256) void flash_kernel(
    const float* __restrict__ sent, const float* __restrict__ v,
    float* __restrict__ partML, float* __restrict__ partP)
{
    const int b = blockIdx.y;
    const int ch = blockIdx.x;
    const int t = threadIdx.x;
    const int wave = t >> 6;
    const int lane = t & 63;

    // v fragments in registers: vlo[c][j] = v[c][b][4*lane+j], vhi -> +256
    float vlo[4][4], vhi[4][4];
    #pragma unroll
    for (int c = 0; c < 4; ++c) {
        const float4 lo = *(const float4*)&v[((size_t)c * B + b) * D + lane * 4];
        const float4 hi = *(const float4*)&v[((size_t)c * B + b) * D + 256 + lane * 4];
        vlo[c][0] = lo.x; vlo[c][1] = lo.y; vlo[c][2] = lo.z; vlo[c][3] = lo.w;
        vhi[c][0] = hi.x; vhi[c][1] = hi.y; vhi[c][2] = hi.z; vhi[c][3] = hi.w;
    }

    // this wave's row range
    const size_t sbase = ((size_t)b * S + (size_t)ch * CHUNK + (size_t)wave * ROWS_PER_WAVE) * D;

    float m = -INFINITY, lsum = 0.f;             // state for c = lane&3
    float plo[4][4] = {{0}}, phi[4][4] = {{0}};  // P[c][j] for lane's d-slice

    float xA[4][8], xB[4][8];

    auto loadg = [&](float (&x)[4][8], int g) {
        const float* src = sent + sbase + (size_t)g * 4 * D + lane * 4;
        #pragma unroll
        for (int rr = 0; rr < 4; ++rr) {
            const float4 lo = *(const float4*)(src + rr * D);
            const float4 hi = *(const float4*)(src + rr * D + 256);
            x[rr][0] = lo.x; x[rr][1] = lo.y; x[rr][2] = lo.z; x[rr][3] = lo.w;
            x[rr][4] = hi.x; x[rr][5] = hi.y; x[rr][6] = hi.z; x[rr][7] = hi.w;
        }
    };

    auto compute = [&](float (&x)[4][8]) {
        float s[4];
        #pragma unroll
        for (int rr = 0; rr < 4; ++rr) {
            float a0 = 0.f, a1 = 0.f, a2 = 0.f, a3 = 0.f;
            #pragma unroll
            for (int j = 0; j < 4; ++j) {
                a0 = fmaf(x[rr][j], vlo[0][j], a0); a0 = fmaf(x[rr][4 + j], vhi[0][j], a0);
                a1 = fmaf(x[rr][j], vlo[1][j], a1); a1 = fmaf(x[rr][4 + j], vhi[1][j], a1);
                a2 = fmaf(x[rr][j], vlo[2][j], a2); a2 = fmaf(x[rr][4 + j], vhi[2][j], a2);
                a3 = fmaf(x[rr][j], vlo[3][j], a3); a3 = fmaf(x[rr][4 + j], vhi[3][j], a3);
            }
            // folded 4-value butterfly: 6 shfl, result for c = lane&3
            float u  = (lane & 1) ? a1 : a0;
            float uo = (lane & 1) ? a0 : a1;
            u += __shfl_xor(uo, 1);
            float w_ = (lane & 1) ? a3 : a2;
            float wo = (lane & 1) ? a2 : a3;
            w_ += __shfl_xor(wo, 1);
            float p  = (lane & 2) ? w_ : u;
            float q  = (lane & 2) ? u : w_;
            p += __shfl_xor(q, 2);
            p += __shfl_xor(p, 4);
            p += __shfl_xor(p, 8);
            p += __shfl_xor(p, 16);
            p += __shfl_xor(p, 32);
            s[rr] = p;
        }

        // online softmax update for own c
        const float tm = fmaxf(fmaxf(s[0], s[1]), fmaxf(s[2], s[3]));
        const float mn = fmaxf(m, tm);
        const float cr = __expf(m - mn);    // first group: exp(-inf)=0
        m = mn;
        lsum *= cr;
        float w4[4];
        #pragma unroll
        for (int rr = 0; rr < 4; ++rr) { w4[rr] = __expf(s[rr] - mn); lsum += w4[rr]; }

        // rescale P (broadcast cr_c via readlane: lane c holds c's state)
        #pragma unroll
        for (int c = 0; c < 4; ++c) {
            const float crc = __int_as_float(__builtin_amdgcn_readlane(__float_as_int(cr), c));
            #pragma unroll
            for (int j = 0; j < 4; ++j) { plo[c][j] *= crc; phi[c][j] *= crc; }
        }
        // accumulate P from x regs
        #pragma unroll
        for (int rr = 0; rr < 4; ++rr) {
            #pragma unroll
            for (int c = 0; c < 4; ++c) {
                const float wc = __int_as_float(__builtin_amdgcn_readlane(__float_as_int(w4[rr]), c));
                plo[c][0] = fmaf(wc, x[rr][0], plo[c][0]);
                plo[c][1] = fmaf(wc, x[rr][1], plo[c][1]);
                plo[c][2] = fmaf(wc, x[rr][2], plo[c][2]);
                plo[c][3] = fmaf(wc, x[rr][3], plo[c][3]);
                phi[c][0] = fmaf(wc, x[rr][4], phi[c][0]);
                phi[c][1] = fmaf(wc, x[rr][5], phi[c][1]);
                phi[c][2] = fmaf(wc, x[rr][6], phi[c][2]);
                phi[c][3] = fmaf(wc, x[rr][7], phi[c][3]);
            }
        }
    };

    // software pipeline: loads for group g+1 in flight while computing g
    loadg(xA, 0);
    for (int g = 0; g < NGRP; g += 2) {
        loadg(xB, g + 1);
        compute(xA);
        if (g + 2 < NGRP) loadg(xA, g + 2);
        compute(xB);
    }

    // write per-wave partial
    const int pi = (b * NCHUNK + ch) * NW + wave;
    #pragma unroll
    for (int c = 0; c < 4; ++c) {
        const float4 lo4 = make_float4(plo[c][0], plo[c][1], plo[c][2], plo[c][3]);
        const float4 hi4 = make_float4(phi[c][0], phi[c][1], phi[c][2], phi[c][3]);
        *(float4*)&partP[((size_t)pi * 4 + c) * D + lane * 4] = lo4;
        *(float4*)&partP[((size_t)pi * 4 + c) * D + 256 + lane * 4] = hi4;
    }
    if (lane < 4) {   // lane == c
        partML[(pi * 4 + lane) * 2 + 0] = m;
        partML[(pi * 4 + lane) * 2 + 1] = lsum;
    }
}

// ---------------------------------------------------------------------------
// Kernel 3: merge the 32 per-wave partials per (c,b), normalize, write out.
// ---------------------------------------------------------------------------
__global__ __launch_bounds__(128) void combine_kernel(
    const float* __restrict__ partML, const float* __restrict__ partP,
    float* __restrict__ out)
{
    const int c = blockIdx.x & 3;
    const int b = blockIdx.x >> 2;
    const int t = threadIdx.x;
    const int base_pi = b * NPART;

    float mg = -INFINITY;
    for (int i = 0; i < NPART; ++i)
        mg = fmaxf(mg, partML[((base_pi + i) * 4 + c) * 2 + 0]);

    float lg = 0.f;
    float4 acc = make_float4(0.f, 0.f, 0.f, 0.f);
    for (int i = 0; i < NPART; ++i) {
        const float mi = partML[((base_pi + i) * 4 + c) * 2 + 0];
        const float li = partML[((base_pi + i) * 4 + c) * 2 + 1];
        const float sc = __expf(mi - mg);
        lg += sc * li;
        const float4 p = *(const float4*)&partP[((size_t)(base_pi + i) * 4 + c) * D + t * 4];
        acc.x = fmaf(sc, p.x, acc.x);
        acc.y = fmaf(sc, p.y, acc.y);
        acc.z = fmaf(sc, p.z, acc.z);
        acc.w = fmaf(sc, p.w, acc.w);
    }
    const float inv = 1.f / lg;
    acc.x *= inv; acc.y *= inv; acc.z *= inv; acc.w *= inv;
    *(float4*)&out[((size_t)c * B + b) * D + t * 4] = acc;
}

// ---------------------------------------------------------------------------
extern "C" void kernel_launch(void* const* d_in, const int* in_sizes, int n_in,
                              void* d_out, int out_size, void* d_ws, size_t ws_size,
                              hipStream_t stream)
{
    const float* sent = (const float*)d_in[0];
    const float* c1   = (const float*)d_in[1];
    const float* c2   = (const float*)d_in[2];
    const float* c3   = (const float*)d_in[3];
    const float* c4   = (const float*)d_in[4];
    const float* K    = (const float*)d_in[5];
    const float* bias = (const float*)d_in[6];
    float* out = (float*)d_out;

    // workspace layout (all 16B-aligned)
    float* v      = (float*)d_ws;                                   // 512 KB
    float* partML = (float*)((char*)d_ws + 4 * B * D * 4);          // 64 KB
    float* partP  = (float*)((char*)d_ws + 4 * B * D * 4
                             + B * NPART * 4 * 2 * 4);              // 16 MB

    compute_v_kernel<<<dim3(8, B), 256, 0, stream>>>(K, bias, c1, c2, c3, c4, v);
    flash_kernel<<<dim3(NCHUNK, B), 256, 0, stream>>>(sent, v, partML, partP);
    combine_kernel<<<4 * B, 128, 0, stream>>>(partML, partP, out);
}

// Round 4
// 67.253 us; speedup vs baseline: 1.9872x; 1.1122x over previous
//
#include <hip/hip_runtime.h>
#include <hip/hip_bf16.h>
#include <math.h>

// Problem constants
constexpr int B = 64;
constexpr int S = 2048;
constexpr int D = 512;
constexpr int NCHUNK = 8;           // s-chunks per b
constexpr int CHUNK = S / NCHUNK;   // 256 rows per block
constexpr int NW = 4;               // waves per block
constexpr int ROWS_PER_WAVE = CHUNK / NW;   // 64
constexpr int NGRP = ROWS_PER_WAVE / 4;     // 16 groups of 4 rows
constexpr int NPART = NCHUNK;       // 8 partials per b (after in-block merge)

// ---------------------------------------------------------------------------
// Kernel 1: v[c][b][d] = bias[d] + sum_e K[d][e] * c_c[b][e]
// Folded butterfly: 6 shfl per row (was 24); lanes 0..3 hold c=lane result.
// ---------------------------------------------------------------------------
__global__ __launch_bounds__(256) void compute_v_kernel(
    const float* __restrict__ K, const float* __restrict__ bias,
    const float* __restrict__ c1, const float* __restrict__ c2,
    const float* __restrict__ c3, const float* __restrict__ c4,
    float* __restrict__ v)
{
    const int b = blockIdx.y;
    const int dchunk = blockIdx.x;   // 64 rows each
    __shared__ float c_lds[4][D];

    const float* cptr0 = c1 + (size_t)b * D;
    const float* cptr1 = c2 + (size_t)b * D;
    const float* cptr2 = c3 + (size_t)b * D;
    const float* cptr3 = c4 + (size_t)b * D;
    for (int i = threadIdx.x; i < D; i += 256) {
        c_lds[0][i] = cptr0[i];
        c_lds[1][i] = cptr1[i];
        c_lds[2][i] = cptr2[i];
        c_lds[3][i] = cptr3[i];
    }
    __syncthreads();

    const int wave = threadIdx.x >> 6;
    const int lane = threadIdx.x & 63;

    #pragma unroll
    for (int r = 0; r < 16; ++r) {
        const int d = dchunk * 64 + wave * 16 + r;
        const float* krow = K + (size_t)d * D;
        float a0 = 0.f, a1 = 0.f, a2 = 0.f, a3 = 0.f;
        #pragma unroll
        for (int k = 0; k < D / 64; ++k) {
            const float kv = krow[k * 64 + lane];
            a0 = fmaf(kv, c_lds[0][k * 64 + lane], a0);
            a1 = fmaf(kv, c_lds[1][k * 64 + lane], a1);
            a2 = fmaf(kv, c_lds[2][k * 64 + lane], a2);
            a3 = fmaf(kv, c_lds[3][k * 64 + lane], a3);
        }
        // folded 4-value butterfly: 6 shfl, lane holds total for c = lane&3
        float u  = (lane & 1) ? a1 : a0;
        float uo = (lane & 1) ? a0 : a1;
        u += __shfl_xor(uo, 1);
        float w_ = (lane & 1) ? a3 : a2;
        float wo = (lane & 1) ? a2 : a3;
        w_ += __shfl_xor(wo, 1);
        float p  = (lane & 2) ? w_ : u;
        float q  = (lane & 2) ? u : w_;
        p += __shfl_xor(q, 2);
        p += __shfl_xor(p, 4);
        p += __shfl_xor(p, 8);
        p += __shfl_xor(p, 16);
        p += __shfl_xor(p, 32);
        if (lane < 4)
            v[((size_t)lane * B + b) * D + d] = p + bias[d];
    }
}

// ---------------------------------------------------------------------------
// Kernel 2: flash pass over sent. No LDS in the main loop — each wave streams
// its own 64 rows from global (coalesced 1KB/wave segments), software
// pipelined (xA/xB). Per-wave online softmax (lane's state is c=lane&3);
// lane owns d-slices {4l..4l+3} and {256+4l..+3}. T13 defer-rescale.
// Epilogue: merge the 4 wave-partials in LDS -> one partial per block.
// ---------------------------------------------------------------------------
__global__ __launch_bounds__(256) void flash_kernel(
    const float* __restrict__ sent, const float* __restrict__ v,
    float* __restrict__ partML, float* __restrict__ partP)
{
    const int b = blockIdx.y;
    const int ch = blockIdx.x;
    const int t = threadIdx.x;
    const int wave = t >> 6;
    const int lane = t & 63;

    __shared__ float p_lds[NW][4][D];   // 32 KB (epilogue only)
    __shared__ float ml_lds[NW][4][2];

    // v fragments in registers: vlo[c][j] = v[c][b][4*lane+j], vhi -> +256
    float vlo[4][4], vhi[4][4];
    #pragma unroll
    for (int c = 0; c < 4; ++c) {
        const float4 lo = *(const float4*)&v[((size_t)c * B + b) * D + lane * 4];
        const float4 hi = *(const float4*)&v[((size_t)c * B + b) * D + 256 + lane * 4];
        vlo[c][0] = lo.x; vlo[c][1] = lo.y; vlo[c][2] = lo.z; vlo[c][3] = lo.w;
        vhi[c][0] = hi.x; vhi[c][1] = hi.y; vhi[c][2] = hi.z; vhi[c][3] = hi.w;
    }

    const size_t sbase = ((size_t)b * S + (size_t)ch * CHUNK + (size_t)wave * ROWS_PER_WAVE) * D;

    float m = -INFINITY, lsum = 0.f;             // state for c = lane&3
    float plo[4][4] = {{0}}, phi[4][4] = {{0}};  // P[c][j] for lane's d-slice

    float xA[4][8], xB[4][8];

    auto loadg = [&](float (&x)[4][8], int g) {
        const float* src = sent + sbase + (size_t)g * 4 * D + lane * 4;
        #pragma unroll
        for (int rr = 0; rr < 4; ++rr) {
            const float4 lo = *(const float4*)(src + rr * D);
            const float4 hi = *(const float4*)(src + rr * D + 256);
            x[rr][0] = lo.x; x[rr][1] = lo.y; x[rr][2] = lo.z; x[rr][3] = lo.w;
            x[rr][4] = hi.x; x[rr][5] = hi.y; x[rr][6] = hi.z; x[rr][7] = hi.w;
        }
    };

    auto compute = [&](float (&x)[4][8]) {
        float s[4];
        #pragma unroll
        for (int rr = 0; rr < 4; ++rr) {
            float a0 = 0.f, a1 = 0.f, a2 = 0.f, a3 = 0.f;
            #pragma unroll
            for (int j = 0; j < 4; ++j) {
                a0 = fmaf(x[rr][j], vlo[0][j], a0); a0 = fmaf(x[rr][4 + j], vhi[0][j], a0);
                a1 = fmaf(x[rr][j], vlo[1][j], a1); a1 = fmaf(x[rr][4 + j], vhi[1][j], a1);
                a2 = fmaf(x[rr][j], vlo[2][j], a2); a2 = fmaf(x[rr][4 + j], vhi[2][j], a2);
                a3 = fmaf(x[rr][j], vlo[3][j], a3); a3 = fmaf(x[rr][4 + j], vhi[3][j], a3);
            }
            // folded 4-value butterfly: 6 shfl, result for c = lane&3
            float u  = (lane & 1) ? a1 : a0;
            float uo = (lane & 1) ? a0 : a1;
            u += __shfl_xor(uo, 1);
            float w_ = (lane & 1) ? a3 : a2;
            float wo = (lane & 1) ? a2 : a3;
            w_ += __shfl_xor(wo, 1);
            float p  = (lane & 2) ? w_ : u;
            float q  = (lane & 2) ? u : w_;
            p += __shfl_xor(q, 2);
            p += __shfl_xor(p, 4);
            p += __shfl_xor(p, 8);
            p += __shfl_xor(p, 16);
            p += __shfl_xor(p, 32);
            s[rr] = p;
        }

        // online softmax update for own c, with exact defer-rescale (T13):
        // if no lane's tile-max exceeds its running max, cr==1 -> skip rescale.
        const float tm = fmaxf(fmaxf(s[0], s[1]), fmaxf(s[2], s[3]));
        if (!__all(tm <= m)) {
            const float mn = fmaxf(m, tm);
            const float cr = __expf(m - mn);    // first group: exp(-inf)=0
            m = mn;
            lsum *= cr;
            #pragma unroll
            for (int c = 0; c < 4; ++c) {
                const float crc = __int_as_float(__builtin_amdgcn_readlane(__float_as_int(cr), c));
                #pragma unroll
                for (int j = 0; j < 4; ++j) { plo[c][j] *= crc; phi[c][j] *= crc; }
            }
        }
        float w4[4];
        #pragma unroll
        for (int rr = 0; rr < 4; ++rr) { w4[rr] = __expf(s[rr] - m); lsum += w4[rr]; }

        // accumulate P from x regs
        #pragma unroll
        for (int rr = 0; rr < 4; ++rr) {
            #pragma unroll
            for (int c = 0; c < 4; ++c) {
                const float wc = __int_as_float(__builtin_amdgcn_readlane(__float_as_int(w4[rr]), c));
                plo[c][0] = fmaf(wc, x[rr][0], plo[c][0]);
                plo[c][1] = fmaf(wc, x[rr][1], plo[c][1]);
                plo[c][2] = fmaf(wc, x[rr][2], plo[c][2]);
                plo[c][3] = fmaf(wc, x[rr][3], plo[c][3]);
                phi[c][0] = fmaf(wc, x[rr][4], phi[c][0]);
                phi[c][1] = fmaf(wc, x[rr][5], phi[c][1]);
                phi[c][2] = fmaf(wc, x[rr][6], phi[c][2]);
                phi[c][3] = fmaf(wc, x[rr][7], phi[c][3]);
            }
        }
    };

    // software pipeline: loads for group g+1 in flight while computing g
    loadg(xA, 0);
    for (int g = 0; g < NGRP; g += 2) {
        loadg(xB, g + 1);
        compute(xA);
        if (g + 2 < NGRP) loadg(xA, g + 2);
        compute(xB);
    }

    // ---- in-block merge of the 4 wave-partials (LDS) ----
    #pragma unroll
    for (int c = 0; c < 4; ++c) {
        *(float4*)&p_lds[wave][c][lane * 4] =
            make_float4(plo[c][0], plo[c][1], plo[c][2], plo[c][3]);
        *(float4*)&p_lds[wave][c][256 + lane * 4] =
            make_float4(phi[c][0], phi[c][1], phi[c][2], phi[c][3]);
    }
    if (lane < 4) { ml_lds[wave][lane][0] = m; ml_lds[wave][lane][1] = lsum; }
    __syncthreads();

    // wave w merges c = w across the NW wave-partials
    {
        const int c = wave;
        float mi0 = ml_lds[0][c][0], mi1 = ml_lds[1][c][0];
        float mi2 = ml_lds[2][c][0], mi3 = ml_lds[3][c][0];
        const float mg = fmaxf(fmaxf(mi0, mi1), fmaxf(mi2, mi3));
        const float e0 = __expf(mi0 - mg), e1 = __expf(mi1 - mg);
        const float e2 = __expf(mi2 - mg), e3 = __expf(mi3 - mg);
        const float lg = e0 * ml_lds[0][c][1] + e1 * ml_lds[1][c][1]
                       + e2 * ml_lds[2][c][1] + e3 * ml_lds[3][c][1];

        float4 aLo = make_float4(0.f, 0.f, 0.f, 0.f);
        float4 aHi = make_float4(0.f, 0.f, 0.f, 0.f);
        const float ee[1] = {0};  (void)ee;
        {
            const float4 q0 = *(const float4*)&p_lds[0][c][lane * 4];
            const float4 q1 = *(const float4*)&p_lds[1][c][lane * 4];
            const float4 q2 = *(const float4*)&p_lds[2][c][lane * 4];
            const float4 q3 = *(const float4*)&p_lds[3][c][lane * 4];
            aLo.x = e0*q0.x + e1*q1.x + e2*q2.x + e3*q3.x;
            aLo.y = e0*q0.y + e1*q1.y + e2*q2.y + e3*q3.y;
            aLo.z = e0*q0.z + e1*q1.z + e2*q2.z + e3*q3.z;
            aLo.w = e0*q0.w + e1*q1.w + e2*q2.w + e3*q3.w;
            const float4 r0 = *(const float4*)&p_lds[0][c][256 + lane * 4];
            const float4 r1 = *(const float4*)&p_lds[1][c][256 + lane * 4];
            const float4 r2 = *(const float4*)&p_lds[2][c][256 + lane * 4];
            const float4 r3 = *(const float4*)&p_lds[3][c][256 + lane * 4];
            aHi.x = e0*r0.x + e1*r1.x + e2*r2.x + e3*r3.x;
            aHi.y = e0*r0.y + e1*r1.y + e2*r2.y + e3*r3.y;
            aHi.z = e0*r0.z + e1*r1.z + e2*r2.z + e3*r3.z;
            aHi.w = e0*r0.w + e1*r1.w + e2*r2.w + e3*r3.w;
        }

        const size_t pb = (size_t)(b * NCHUNK + ch) * 4 + c;
        *(float4*)&partP[pb * D + lane * 4] = aLo;
        *(float4*)&partP[pb * D + 256 + lane * 4] = aHi;
        if (lane == 0) {
            partML[pb * 2 + 0] = mg;
            partML[pb * 2 + 1] = lg;
        }
    }
}

// ---------------------------------------------------------------------------
// Kernel 3: merge the NCHUNK partials per (c,b), normalize, write out.
// ---------------------------------------------------------------------------
__global__ __launch_bounds__(128) void combine_kernel(
    const float* __restrict__ partML, const float* __restrict__ partP,
    float* __restrict__ out)
{
    const int c = blockIdx.x & 3;
    const int b = blockIdx.x >> 2;
    const int t = threadIdx.x;

    float mg = -INFINITY;
    #pragma unroll
    for (int i = 0; i < NPART; ++i)
        mg = fmaxf(mg, partML[((size_t)(b * NCHUNK + i) * 4 + c) * 2 + 0]);

    float lg = 0.f;
    float4 acc = make_float4(0.f, 0.f, 0.f, 0.f);
    #pragma unroll
    for (int i = 0; i < NPART; ++i) {
        const size_t pb = (size_t)(b * NCHUNK + i) * 4 + c;
        const float mi = partML[pb * 2 + 0];
        const float li = partML[pb * 2 + 1];
        const float sc = __expf(mi - mg);
        lg += sc * li;
        const float4 p = *(const float4*)&partP[pb * D + t * 4];
        acc.x = fmaf(sc, p.x, acc.x);
        acc.y = fmaf(sc, p.y, acc.y);
        acc.z = fmaf(sc, p.z, acc.z);
        acc.w = fmaf(sc, p.w, acc.w);
    }
    const float inv = 1.f / lg;
    acc.x *= inv; acc.y *= inv; acc.z *= inv; acc.w *= inv;
    *(float4*)&out[((size_t)c * B + b) * D + t * 4] = acc;
}

// ---------------------------------------------------------------------------
extern "C" void kernel_launch(void* const* d_in, const int* in_sizes, int n_in,
                              void* d_out, int out_size, void* d_ws, size_t ws_size,
                              hipStream_t stream)
{
    const float* sent = (const float*)d_in[0];
    const float* c1   = (const float*)d_in[1];
    const float* c2   = (const float*)d_in[2];
    const float* c3   = (const float*)d_in[3];
    const float* c4   = (const float*)d_in[4];
    const float* K    = (const float*)d_in[5];
    const float* bias = (const float*)d_in[6];
    float* out = (float*)d_out;

    // workspace layout (all 16B-aligned)
    float* v      = (float*)d_ws;                                   // 512 KB
    float* partML = (float*)((char*)d_ws + 4 * B * D * 4);          // 16 KB
    float* partP  = (float*)((char*)d_ws + 4 * B * D * 4
                             + B * NCHUNK * 4 * 2 * 4);             // 4.2 MB

    compute_v_kernel<<<dim3(8, B), 256, 0, stream>>>(K, bias, c1, c2, c3, c4, v);
    flash_kernel<<<dim3(NCHUNK, B), 256, 0, stream>>>(sent, v, partML, partP);
    combine_kernel<<<4 * B, 128, 0, stream>>>(partML, partP, out);
}